// Round 12
// baseline (1493.458 us; speedup 1.0000x reference)
//
#include <hip/hip_runtime.h>

#define TT 20
#define HH 64
#define RSZ 12288      // dst nodes per bin range (48 KB LDS)
#define NSL 8          // edge slices

typedef __attribute__((ext_vector_type(8))) short short8;   // 8 bf16 (MFMA A/B frag)
typedef __attribute__((ext_vector_type(4))) float f32x4;    // MFMA C/D frag

__device__ __forceinline__ float fast_tanh(float a) {
    a = fminf(fmaxf(a, -12.0f), 12.0f);
    float e = __builtin_amdgcn_exp2f(a * 2.885390081777927f);
    return (e - 1.0f) * __builtin_amdgcn_rcpf(e + 1.0f);
}

__device__ __forceinline__ unsigned fbits(float f) { union { float f; unsigned u; } v; v.f = f; return v.u; }
__device__ __forceinline__ float bcast(unsigned u) { union { float f; unsigned u; } v; v.u = u; return v.f; }

// deg histogram via LDS bins; block (r,s): range r of dsts, slice s of edges.
// Flush overwrites exclusive replica region -> no global atomics, no memset.
__global__ __launch_bounds__(256) void k_deg_bin(const int* __restrict__ ei,
                                                 unsigned* __restrict__ degrep,
                                                 int N, int E, int R) {
    __shared__ unsigned bin[RSZ];
    const int r = blockIdx.x % R;
    const int s = blockIdx.x / R;
    const int base = r * RSZ;
    for (int i = threadIdx.x; i < RSZ; i += 256) bin[i] = 0;
    __syncthreads();
    const long long eb = (long long)s * E / NSL;
    const long long ee = (long long)(s + 1) * E / NSL;
    const int2* ei2 = (const int2*)ei;
    for (long long e = eb + threadIdx.x; e < ee; e += 256) {
        int2 p = ei2[e];
        unsigned u = (unsigned)(p.y - base);
        if (u < RSZ) atomicAdd(&bin[u], 1u);
    }
    __syncthreads();
    const int lim = min(RSZ, N - base);
    unsigned* dst = degrep + (size_t)s * N + base;
    for (int i = threadIdx.x; i < lim; i += 256) dst[i] = bin[i];
}

// Pure MFMA RNN: 4 independent waves/block, 16 nodes each, wave-private LDS.
// Epilogue reduces deg replicas and writes dinv[n], w[n] = dinv*(h.v).
__global__ __launch_bounds__(256, 3) void k_fused(
    const float* __restrict__ x,
    const float* __restrict__ W_ih, const float* __restrict__ b_ih,
    const float* __restrict__ W_hh, const float* __restrict__ b_hh,
    const float* __restrict__ W_gcn, const float* __restrict__ W_fc,
    const unsigned* __restrict__ degrep,
    float* __restrict__ dinv, float* __restrict__ wv_out, int N)
{
    __shared__ __align__(16) unsigned short sHh[4][1024];
    __shared__ __align__(16) unsigned short sHl[4][1024];
    __shared__ __align__(16) float sX[4][16 * TT];

    const int t    = threadIdx.x;
    const int w    = t >> 6;
    const int l    = t & 63;
    const int nl   = l & 15;
    const int quad = l >> 4;
    const int n0   = blockIdx.x * 64 + w * 16;

    unsigned short* hh = sHh[w];
    unsigned short* hl = sHl[w];
    float*          sx = sX[w];

    // stage x (16 nodes x 20 steps, transposed [step][node])
    for (int i = l; i < 16 * TT; i += 64) {
        int nn = i / TT, tt = i - nn * TT;
        int n = n0 + nn; if (n >= N) n = N - 1;
        sx[tt * 16 + nn] = x[(size_t)n * TT + tt];
    }
    // zero h
    {
        uint4 zz = {0, 0, 0, 0};
        uint4* ph = (uint4*)hh;
        uint4* pl = (uint4*)hl;
#pragma unroll
        for (int i = 0; i < 2; ++i) { ph[l + 64 * i] = zz; pl[l + 64 * i] = zz; }
    }

    // W_hh -> hi/lo bf16 B-fragments (registers, trunc-split)
    short8 Bh[4][2], Bl[4][2];
#pragma unroll
    for (int tt2 = 0; tt2 < 4; ++tt2)
#pragma unroll
        for (int kc = 0; kc < 2; ++kc) {
            const float* wr = W_hh + (size_t)(16 * tt2 + nl) * HH + kc * 32 + quad * 8;
            float4 w0 = *(const float4*)(wr);
            float4 w1 = *(const float4*)(wr + 4);
            float wvv[8] = {w0.x, w0.y, w0.z, w0.w, w1.x, w1.y, w1.z, w1.w};
            short8 sh, sl;
#pragma unroll
            for (int j = 0; j < 8; ++j) {
                unsigned u  = fbits(wvv[j]);
                unsigned hb = u & 0xffff0000u;
                float lo = wvv[j] - bcast(hb);
                sh[j] = (short)(hb >> 16);
                sl[j] = (short)(fbits(lo) >> 16);
            }
            Bh[tt2][kc] = sh; Bl[tt2][kc] = sl;
        }

    // v = W_gcn^T w_fc
    float vl = 0.0f;
#pragma unroll 8
    for (int j = 0; j < HH; ++j) vl = fmaf(W_fc[j], W_gcn[j * HH + l], vl);

    float wih4[4], bs4[4], vv[4];
#pragma unroll
    for (int tt2 = 0; tt2 < 4; ++tt2) {
        int n = nl + 16 * tt2;
        wih4[tt2] = W_ih[n];
        bs4[tt2]  = b_ih[n] + b_hh[n];
        vv[tt2]   = __shfl(vl, n, 64);
    }

    const int ra = (l ^ ((l >> 4) & 1)) * 8;   // A-read offset (shorts)

    f32x4 C[4];

    for (int step = 0; step < TT; ++step) {
        const float4 xr = *(const float4*)&sx[step * 16 + quad * 4];
#pragma unroll
        for (int tt2 = 0; tt2 < 4; ++tt2) {
            C[tt2][0] = fmaf(xr.x, wih4[tt2], bs4[tt2]);
            C[tt2][1] = fmaf(xr.y, wih4[tt2], bs4[tt2]);
            C[tt2][2] = fmaf(xr.z, wih4[tt2], bs4[tt2]);
            C[tt2][3] = fmaf(xr.w, wih4[tt2], bs4[tt2]);
        }

#pragma unroll
        for (int kc = 0; kc < 2; ++kc) {
            short8 Ah = *(const short8*)&hh[kc * 512 + ra];
            short8 Al = *(const short8*)&hl[kc * 512 + ra];
#pragma unroll
            for (int tt2 = 0; tt2 < 4; ++tt2) {
                C[tt2] = __builtin_amdgcn_mfma_f32_16x16x32_bf16(Ah, Bh[tt2][kc], C[tt2], 0, 0, 0);
                C[tt2] = __builtin_amdgcn_mfma_f32_16x16x32_bf16(Ah, Bl[tt2][kc], C[tt2], 0, 0, 0);
                C[tt2] = __builtin_amdgcn_mfma_f32_16x16x32_bf16(Al, Bh[tt2][kc], C[tt2], 0, 0, 0);
            }
        }

        // tanh + trunc-split + neighbor-pack + swizzled write back
#pragma unroll
        for (int tt2 = 0; tt2 < 4; ++tt2) {
            const int kc_d = tt2 >> 1;
            const int qa   = (nl >> 3) + 2 * (tt2 & 1);
#pragma unroll
            for (int r = 0; r < 4; ++r) {
                float hv = fast_tanh(C[tt2][r]);
                C[tt2][r] = hv;
                unsigned um = fbits(hv);
                unsigned un = (unsigned)__shfl_xor((int)um, 1, 64);
                if (!(nl & 1)) {
                    unsigned hiw = (um >> 16) | (un & 0xffff0000u);
                    float lm = hv - bcast(um & 0xffff0000u);
                    float ln = bcast(un) - bcast(un & 0xffff0000u);
                    unsigned low = (fbits(lm) >> 16) | (fbits(ln) & 0xffff0000u);
                    const int m   = quad * 4 + r;
                    const int la  = m + 16 * qa;
                    const int idx = kc_d * 512 + (la ^ ((la >> 4) & 1)) * 8 + (nl & 7);
                    *(unsigned*)&hh[idx] = hiw;
                    *(unsigned*)&hl[idx] = low;
                }
            }
        }
    }

    // epilogue: z = h.v ; reduce deg replicas ; write dinv, w = dinv*z
#pragma unroll
    for (int r = 0; r < 4; ++r) {
        float p = 0.0f;
#pragma unroll
        for (int tt2 = 0; tt2 < 4; ++tt2) p = fmaf(C[tt2][r], vv[tt2], p);
        p += __shfl_xor(p, 1, 64);
        p += __shfl_xor(p, 2, 64);
        p += __shfl_xor(p, 4, 64);
        p += __shfl_xor(p, 8, 64);
        if (nl == 0) {
            const int n = n0 + quad * 4 + r;
            if (n < N) {
                unsigned d = 0;
#pragma unroll
                for (int s = 0; s < NSL; ++s) d += degrep[(size_t)s * N + n];
                float di = __frsqrt_rn((float)d + 1.0f);
                dinv[n] = di;
                wv_out[n] = di * p;
            }
        }
    }
}

// S aggregation via LDS float bins; S[d] += w[s] for edges in (range, slice).
__global__ __launch_bounds__(256) void k_edge_bin(const int* __restrict__ ei,
                                                  const float* __restrict__ w,
                                                  float* __restrict__ Srep,
                                                  int N, int E, int R) {
    __shared__ float bin[RSZ];
    const int r = blockIdx.x % R;
    const int s = blockIdx.x / R;
    const int base = r * RSZ;
    for (int i = threadIdx.x; i < RSZ; i += 256) bin[i] = 0.0f;
    __syncthreads();
    const long long eb = (long long)s * E / NSL;
    const long long ee = (long long)(s + 1) * E / NSL;
    const int2* ei2 = (const int2*)ei;
    for (long long e = eb + threadIdx.x; e < ee; e += 256) {
        int2 p = ei2[e];
        unsigned u = (unsigned)(p.y - base);
        if (u < RSZ) atomicAdd(&bin[u], w[p.x]);
    }
    __syncthreads();
    const int lim = min(RSZ, N - base);
    float* dst = Srep + (size_t)s * N + base;
    for (int i = threadIdx.x; i < lim; i += 256) dst[i] = bin[i];
}

// out = dinv*S + dinv*w + c,  c = w_fc.b_gcn + b_fc
__global__ void k_final(const float* __restrict__ dinv, const float* __restrict__ Srep,
                        const float* __restrict__ w,
                        const float* __restrict__ b_gcn, const float* __restrict__ W_fc,
                        const float* __restrict__ b_fc,
                        float* __restrict__ out, int N)
{
    float c = b_fc[0];
#pragma unroll 8
    for (int j = 0; j < HH; ++j) c = fmaf(W_fc[j], b_gcn[j], c);
    int n = blockIdx.x * blockDim.x + threadIdx.x;
    if (n >= N) return;
    float S = 0.0f;
#pragma unroll
    for (int s = 0; s < NSL; ++s) S += Srep[(size_t)s * N + n];
    float d = dinv[n];
    out[n] = fmaf(d, S, fmaf(d, w[n], c));
}

extern "C" void kernel_launch(void* const* d_in, const int* in_sizes, int n_in,
                              void* d_out, int out_size, void* d_ws, size_t ws_size,
                              hipStream_t stream)
{
    const float* x     = (const float*)d_in[0];
    const int*   ei    = (const int*)d_in[1];
    const float* W_ih  = (const float*)d_in[2];
    const float* b_ih  = (const float*)d_in[3];
    const float* W_hh  = (const float*)d_in[4];
    const float* b_hh  = (const float*)d_in[5];
    const float* W_gcn = (const float*)d_in[6];
    const float* b_gcn = (const float*)d_in[7];
    const float* W_fc  = (const float*)d_in[8];
    const float* b_fc  = (const float*)d_in[9];
    float* out = (float*)d_out;

    const int N = in_sizes[0] / TT;
    const int E = in_sizes[1] / 2;
    const int R = (N + RSZ - 1) / RSZ;

    char* ws = (char*)d_ws;
    size_t off = 0;
    auto alloc = [&](size_t bytes) { void* p = ws + off; off += (bytes + 255) & ~(size_t)255; return p; };
    unsigned* degrep = (unsigned*)alloc((size_t)NSL * N * 4);
    float*    Srep   = (float*)   alloc((size_t)NSL * N * 4);
    float*    dinv   = (float*)   alloc((size_t)N * 4);
    float*    w      = (float*)   alloc((size_t)N * 4);
    // no memsets: every replica byte is overwritten by its (range, slice) owner

    const int rnnBlocks = (N + 63) / 64;
    k_deg_bin <<<R * NSL, 256, 0, stream>>>(ei, degrep, N, E, R);
    k_fused   <<<rnnBlocks, 256, 0, stream>>>(x, W_ih, b_ih, W_hh, b_hh,
                                              W_gcn, W_fc, degrep, dinv, w, N);
    k_edge_bin<<<R * NSL, 256, 0, stream>>>(ei, w, Srep, N, E, R);
    k_final   <<<(N + 255) / 256, 256, 0, stream>>>(dinv, Srep, w, b_gcn, W_fc, b_fc, out, N);
}

// Round 13
// 296.722 us; speedup vs baseline: 5.0332x; 5.0332x over previous
//
#include <hip/hip_runtime.h>

#define TT 20
#define HH 64
#define RSZ 16384      // dst nodes per bin range (64 KB LDS = per-block max)
#define NSL 64         // edge slices (parallelism): R*NSL = 448 blocks

typedef __attribute__((ext_vector_type(8))) short short8;   // 8 bf16 (MFMA A/B frag)
typedef __attribute__((ext_vector_type(4))) float f32x4;    // MFMA C/D frag

__device__ __forceinline__ float fast_tanh(float a) {
    a = fminf(fmaxf(a, -12.0f), 12.0f);
    float e = __builtin_amdgcn_exp2f(a * 2.885390081777927f);
    return (e - 1.0f) * __builtin_amdgcn_rcpf(e + 1.0f);
}

__device__ __forceinline__ unsigned fbits(float f) { union { float f; unsigned u; } v; v.f = f; return v.u; }
__device__ __forceinline__ float bcast(unsigned u) { union { float f; unsigned u; } v; v.u = u; return v.f; }

// deg histogram via LDS bins. Block (r,s): dst range r, edge slice s.
// 1024 threads -> ~49 load iterations; 32 waves/CU hide L3 latency.
__global__ __launch_bounds__(1024) void k_deg_bin(const int* __restrict__ ei,
                                                  unsigned* __restrict__ degrep,
                                                  int N, int E, int R) {
    __shared__ unsigned bin[RSZ];                 // 64 KB
    const int r = blockIdx.x % R;
    const int s = blockIdx.x / R;
    const int base = r * RSZ;
    for (int i = threadIdx.x; i < RSZ; i += 1024) bin[i] = 0;
    __syncthreads();
    const long long eb = (long long)s * E / NSL;
    const long long ee = (long long)(s + 1) * E / NSL;
    const int2* ei2 = (const int2*)ei;
    for (long long e = eb + threadIdx.x; e < ee; e += 1024) {
        int2 p = ei2[e];
        unsigned u = (unsigned)(p.y - base);
        if (u < RSZ) atomicAdd(&bin[u], 1u);
    }
    __syncthreads();
    const int lim = min(RSZ, N - base);
    unsigned* dst = degrep + (size_t)s * N + base;
    for (int i = threadIdx.x; i < lim; i += 1024) dst[i] = bin[i];
}

// Pure MFMA RNN: 4 independent waves/block, 16 nodes each, wave-private LDS,
// no barriers. Writes z[n] = h_n . v.
__global__ __launch_bounds__(256, 3) void k_rnn(
    const float* __restrict__ x,
    const float* __restrict__ W_ih, const float* __restrict__ b_ih,
    const float* __restrict__ W_hh, const float* __restrict__ b_hh,
    const float* __restrict__ W_gcn, const float* __restrict__ W_fc,
    float* __restrict__ z, int N)
{
    __shared__ __align__(16) unsigned short sHh[4][1024];
    __shared__ __align__(16) unsigned short sHl[4][1024];
    __shared__ __align__(16) float sX[4][16 * TT];

    const int t    = threadIdx.x;
    const int w    = t >> 6;
    const int l    = t & 63;
    const int nl   = l & 15;
    const int quad = l >> 4;
    const int n0   = blockIdx.x * 64 + w * 16;

    unsigned short* hh = sHh[w];
    unsigned short* hl = sHl[w];
    float*          sx = sX[w];

    // stage x (16 nodes x 20 steps, transposed [step][node])
    for (int i = l; i < 16 * TT; i += 64) {
        int nn = i / TT, tt = i - nn * TT;
        int n = n0 + nn; if (n >= N) n = N - 1;
        sx[tt * 16 + nn] = x[(size_t)n * TT + tt];
    }
    // zero h
    {
        uint4 zz = {0, 0, 0, 0};
        uint4* ph = (uint4*)hh;
        uint4* pl = (uint4*)hl;
#pragma unroll
        for (int i = 0; i < 2; ++i) { ph[l + 64 * i] = zz; pl[l + 64 * i] = zz; }
    }

    // W_hh -> hi/lo bf16 B-fragments (registers, trunc-split)
    short8 Bh[4][2], Bl[4][2];
#pragma unroll
    for (int tt2 = 0; tt2 < 4; ++tt2)
#pragma unroll
        for (int kc = 0; kc < 2; ++kc) {
            const float* wr = W_hh + (size_t)(16 * tt2 + nl) * HH + kc * 32 + quad * 8;
            float4 w0 = *(const float4*)(wr);
            float4 w1 = *(const float4*)(wr + 4);
            float wvv[8] = {w0.x, w0.y, w0.z, w0.w, w1.x, w1.y, w1.z, w1.w};
            short8 sh, sl;
#pragma unroll
            for (int j = 0; j < 8; ++j) {
                unsigned u  = fbits(wvv[j]);
                unsigned hb = u & 0xffff0000u;
                float lo = wvv[j] - bcast(hb);
                sh[j] = (short)(hb >> 16);
                sl[j] = (short)(fbits(lo) >> 16);
            }
            Bh[tt2][kc] = sh; Bl[tt2][kc] = sl;
        }

    // v = W_gcn^T w_fc
    float vl = 0.0f;
#pragma unroll 8
    for (int j = 0; j < HH; ++j) vl = fmaf(W_fc[j], W_gcn[j * HH + l], vl);

    float wih4[4], bs4[4], vv[4];
#pragma unroll
    for (int tt2 = 0; tt2 < 4; ++tt2) {
        int n = nl + 16 * tt2;
        wih4[tt2] = W_ih[n];
        bs4[tt2]  = b_ih[n] + b_hh[n];
        vv[tt2]   = __shfl(vl, n, 64);
    }

    const int ra = (l ^ ((l >> 4) & 1)) * 8;   // A-read offset (shorts)

    f32x4 C[4];

    for (int step = 0; step < TT; ++step) {
        const float4 xr = *(const float4*)&sx[step * 16 + quad * 4];
#pragma unroll
        for (int tt2 = 0; tt2 < 4; ++tt2) {
            C[tt2][0] = fmaf(xr.x, wih4[tt2], bs4[tt2]);
            C[tt2][1] = fmaf(xr.y, wih4[tt2], bs4[tt2]);
            C[tt2][2] = fmaf(xr.z, wih4[tt2], bs4[tt2]);
            C[tt2][3] = fmaf(xr.w, wih4[tt2], bs4[tt2]);
        }

#pragma unroll
        for (int kc = 0; kc < 2; ++kc) {
            short8 Ah = *(const short8*)&hh[kc * 512 + ra];
            short8 Al = *(const short8*)&hl[kc * 512 + ra];
#pragma unroll
            for (int tt2 = 0; tt2 < 4; ++tt2) {
                C[tt2] = __builtin_amdgcn_mfma_f32_16x16x32_bf16(Ah, Bh[tt2][kc], C[tt2], 0, 0, 0);
                C[tt2] = __builtin_amdgcn_mfma_f32_16x16x32_bf16(Ah, Bl[tt2][kc], C[tt2], 0, 0, 0);
                C[tt2] = __builtin_amdgcn_mfma_f32_16x16x32_bf16(Al, Bh[tt2][kc], C[tt2], 0, 0, 0);
            }
        }

        // tanh + trunc-split + neighbor-pack + swizzled write back
#pragma unroll
        for (int tt2 = 0; tt2 < 4; ++tt2) {
            const int kc_d = tt2 >> 1;
            const int qa   = (nl >> 3) + 2 * (tt2 & 1);
#pragma unroll
            for (int r = 0; r < 4; ++r) {
                float hv = fast_tanh(C[tt2][r]);
                C[tt2][r] = hv;
                unsigned um = fbits(hv);
                unsigned un = (unsigned)__shfl_xor((int)um, 1, 64);
                if (!(nl & 1)) {
                    unsigned hiw = (um >> 16) | (un & 0xffff0000u);
                    float lm = hv - bcast(um & 0xffff0000u);
                    float ln = bcast(un) - bcast(un & 0xffff0000u);
                    unsigned low = (fbits(lm) >> 16) | (fbits(ln) & 0xffff0000u);
                    const int m   = quad * 4 + r;
                    const int la  = m + 16 * qa;
                    const int idx = kc_d * 512 + (la ^ ((la >> 4) & 1)) * 8 + (nl & 7);
                    *(unsigned*)&hh[idx] = hiw;
                    *(unsigned*)&hl[idx] = low;
                }
            }
        }
    }

    // epilogue: z = h.v
#pragma unroll
    for (int r = 0; r < 4; ++r) {
        float p = 0.0f;
#pragma unroll
        for (int tt2 = 0; tt2 < 4; ++tt2) p = fmaf(C[tt2][r], vv[tt2], p);
        p += __shfl_xor(p, 1, 64);
        p += __shfl_xor(p, 2, 64);
        p += __shfl_xor(p, 4, 64);
        p += __shfl_xor(p, 8, 64);
        if (nl == 0) {
            const int n = n0 + quad * 4 + r;
            if (n < N) z[n] = p;
        }
    }
}

// reduce deg replicas; dinv = rsqrt(deg+1); w = dinv*z
__global__ __launch_bounds__(256) void k_w(const unsigned* __restrict__ degrep,
                                           const float* __restrict__ z,
                                           float* __restrict__ dinv,
                                           float* __restrict__ w, int N) {
    int n = blockIdx.x * blockDim.x + threadIdx.x;
    if (n >= N) return;
    unsigned d = 0;
#pragma unroll 8
    for (int s = 0; s < NSL; ++s) d += degrep[(size_t)s * N + n];
    float di = __frsqrt_rn((float)d + 1.0f);
    dinv[n] = di;
    w[n] = di * z[n];
}

// S aggregation via LDS float bins, same (range, slice) structure.
__global__ __launch_bounds__(1024) void k_edge_bin(const int* __restrict__ ei,
                                                   const float* __restrict__ w,
                                                   float* __restrict__ Srep,
                                                   int N, int E, int R) {
    __shared__ float bin[RSZ];                    // 64 KB
    const int r = blockIdx.x % R;
    const int s = blockIdx.x / R;
    const int base = r * RSZ;
    for (int i = threadIdx.x; i < RSZ; i += 1024) bin[i] = 0.0f;
    __syncthreads();
    const long long eb = (long long)s * E / NSL;
    const long long ee = (long long)(s + 1) * E / NSL;
    const int2* ei2 = (const int2*)ei;
    for (long long e = eb + threadIdx.x; e < ee; e += 1024) {
        int2 p = ei2[e];
        unsigned u = (unsigned)(p.y - base);
        if (u < RSZ) atomicAdd(&bin[u], w[p.x]);
    }
    __syncthreads();
    const int lim = min(RSZ, N - base);
    float* dst = Srep + (size_t)s * N + base;
    for (int i = threadIdx.x; i < lim; i += 1024) dst[i] = bin[i];
}

// out = dinv*(sum S_rep) + dinv*w + c,  c = w_fc.b_gcn + b_fc
__global__ __launch_bounds__(256) void k_final(const float* __restrict__ dinv,
                                               const float* __restrict__ Srep,
                                               const float* __restrict__ w,
                                               const float* __restrict__ b_gcn,
                                               const float* __restrict__ W_fc,
                                               const float* __restrict__ b_fc,
                                               float* __restrict__ out, int N)
{
    float c = b_fc[0];
#pragma unroll 8
    for (int j = 0; j < HH; ++j) c = fmaf(W_fc[j], b_gcn[j], c);
    int n = blockIdx.x * blockDim.x + threadIdx.x;
    if (n >= N) return;
    float S = 0.0f;
#pragma unroll 8
    for (int s = 0; s < NSL; ++s) S += Srep[(size_t)s * N + n];
    float d = dinv[n];
    out[n] = fmaf(d, S, fmaf(d, w[n], c));
}

extern "C" void kernel_launch(void* const* d_in, const int* in_sizes, int n_in,
                              void* d_out, int out_size, void* d_ws, size_t ws_size,
                              hipStream_t stream)
{
    const float* x     = (const float*)d_in[0];
    const int*   ei    = (const int*)d_in[1];
    const float* W_ih  = (const float*)d_in[2];
    const float* b_ih  = (const float*)d_in[3];
    const float* W_hh  = (const float*)d_in[4];
    const float* b_hh  = (const float*)d_in[5];
    const float* W_gcn = (const float*)d_in[6];
    const float* b_gcn = (const float*)d_in[7];
    const float* W_fc  = (const float*)d_in[8];
    const float* b_fc  = (const float*)d_in[9];
    float* out = (float*)d_out;

    const int N = in_sizes[0] / TT;
    const int E = in_sizes[1] / 2;
    const int R = (N + RSZ - 1) / RSZ;

    char* ws = (char*)d_ws;
    size_t off = 0;
    auto alloc = [&](size_t bytes) { void* p = ws + off; off += (bytes + 255) & ~(size_t)255; return p; };
    unsigned* degrep = (unsigned*)alloc((size_t)NSL * N * 4);
    float*    Srep   = (float*)   alloc((size_t)NSL * N * 4);
    float*    z      = (float*)   alloc((size_t)N * 4);
    float*    dinv   = (float*)   alloc((size_t)N * 4);
    float*    w      = (float*)   alloc((size_t)N * 4);
    // no memsets: every replica byte is overwritten by its (range, slice) owner

    const int rnnBlocks = (N + 63) / 64;
    k_deg_bin <<<R * NSL, 1024, 0, stream>>>(ei, degrep, N, E, R);
    k_rnn     <<<rnnBlocks, 256, 0, stream>>>(x, W_ih, b_ih, W_hh, b_hh,
                                              W_gcn, W_fc, z, N);
    k_w       <<<(N + 255) / 256, 256, 0, stream>>>(degrep, z, dinv, w, N);
    k_edge_bin<<<R * NSL, 1024, 0, stream>>>(ei, w, Srep, N, E, R);
    k_final   <<<(N + 255) / 256, 256, 0, stream>>>(dinv, Srep, w, b_gcn, W_fc, b_fc, out, N);
}

// Round 14
// 245.223 us; speedup vs baseline: 6.0902x; 1.2100x over previous
//
#include <hip/hip_runtime.h>

#define TT 20
#define HH 64
#define RSZ 16384      // fp32 S-bin range (64 KB LDS)
#define DRSZ 32768     // u16 deg-bin range (64 KB LDS as 16384 u32 words)
#define NSL 64         // edge slices

typedef __attribute__((ext_vector_type(8))) short short8;   // 8 bf16 (MFMA A/B frag)
typedef __attribute__((ext_vector_type(4))) float f32x4;    // MFMA C/D frag

__device__ __forceinline__ unsigned fbits(float f) { union { float f; unsigned u; } v; v.f = f; return v.u; }
__device__ __forceinline__ float bcast(unsigned u) { union { float f; unsigned u; } v; v.u = u; return v.f; }

// deg histogram via packed-u16 LDS bins. Block (r,s): dst range r, edge slice s.
// Low-half counters can't carry into high half (deg << 65536).
__global__ __launch_bounds__(1024) void k_deg_bin(const int* __restrict__ ei,
                                                  unsigned* __restrict__ degrep,
                                                  int N, int E, int R, int N2) {
    __shared__ unsigned bin[DRSZ / 2];            // 64 KB
    const int r = blockIdx.x % R;
    const int s = blockIdx.x / R;
    const int base = r * DRSZ;
    for (int i = threadIdx.x; i < DRSZ / 2; i += 1024) bin[i] = 0;
    __syncthreads();
    const long long eb = (long long)s * E / NSL;
    const long long ee = (long long)(s + 1) * E / NSL;
    const int2* ei2 = (const int2*)ei;
    for (long long e = eb + threadIdx.x; e < ee; e += 1024) {
        int2 p = ei2[e];
        unsigned u = (unsigned)(p.y - base);
        if (u < DRSZ) atomicAdd(&bin[u >> 1], 1u << ((u & 1) << 4));
    }
    __syncthreads();
    const int lim = min(DRSZ, N - base);          // elements in range
    const int words = (lim + 1) >> 1;
    unsigned* dst = degrep + (size_t)s * N2 + (base >> 1);
    for (int i = threadIdx.x; i < words; i += 1024) dst[i] = bin[i];
}

// Pure MFMA RNN: 4 independent waves/block, 16 nodes each, wave-private LDS,
// no barriers. Writes z[n] = h_n . v.
__global__ __launch_bounds__(256, 3) void k_rnn(
    const float* __restrict__ x,
    const float* __restrict__ W_ih, const float* __restrict__ b_ih,
    const float* __restrict__ W_hh, const float* __restrict__ b_hh,
    const float* __restrict__ W_gcn, const float* __restrict__ W_fc,
    float* __restrict__ z, int N)
{
    __shared__ __align__(16) unsigned short sHh[4][1024];
    __shared__ __align__(16) unsigned short sHl[4][1024];
    __shared__ __align__(16) float sX[4][16 * TT];

    const int t    = threadIdx.x;
    const int w    = t >> 6;
    const int l    = t & 63;
    const int nl   = l & 15;
    const int quad = l >> 4;
    const int n0   = blockIdx.x * 64 + w * 16;

    unsigned short* hh = sHh[w];
    unsigned short* hl = sHl[w];
    float*          sx = sX[w];

    // stage x (16 nodes x 20 steps, transposed [step][node])
    for (int i = l; i < 16 * TT; i += 64) {
        int nn = i / TT, tt = i - nn * TT;
        int n = n0 + nn; if (n >= N) n = N - 1;
        sx[tt * 16 + nn] = x[(size_t)n * TT + tt];
    }
    // zero h
    {
        uint4 zz = {0, 0, 0, 0};
        uint4* ph = (uint4*)hh;
        uint4* pl = (uint4*)hl;
#pragma unroll
        for (int i = 0; i < 2; ++i) { ph[l + 64 * i] = zz; pl[l + 64 * i] = zz; }
    }

    // W_hh -> hi/lo bf16 B-fragments (registers, trunc-split)
    short8 Bh[4][2], Bl[4][2];
#pragma unroll
    for (int tt2 = 0; tt2 < 4; ++tt2)
#pragma unroll
        for (int kc = 0; kc < 2; ++kc) {
            const float* wr = W_hh + (size_t)(16 * tt2 + nl) * HH + kc * 32 + quad * 8;
            float4 w0 = *(const float4*)(wr);
            float4 w1 = *(const float4*)(wr + 4);
            float wvv[8] = {w0.x, w0.y, w0.z, w0.w, w1.x, w1.y, w1.z, w1.w};
            short8 sh, sl;
#pragma unroll
            for (int j = 0; j < 8; ++j) {
                unsigned u  = fbits(wvv[j]);
                unsigned hb = u & 0xffff0000u;
                float lo = wvv[j] - bcast(hb);
                sh[j] = (short)(hb >> 16);
                sl[j] = (short)(fbits(lo) >> 16);
            }
            Bh[tt2][kc] = sh; Bl[tt2][kc] = sl;
        }

    // v = W_gcn^T w_fc
    float vl = 0.0f;
#pragma unroll 8
    for (int j = 0; j < HH; ++j) vl = fmaf(W_fc[j], W_gcn[j * HH + l], vl);

    float wih4[4], bs4[4], vv[4];
#pragma unroll
    for (int tt2 = 0; tt2 < 4; ++tt2) {
        int n = nl + 16 * tt2;
        wih4[tt2] = W_ih[n];
        bs4[tt2]  = b_ih[n] + b_hh[n];
        vv[tt2]   = __shfl(vl, n, 64);
    }

    const int ra = (l ^ ((l >> 4) & 1)) * 8;   // A-read offset (shorts)

    f32x4 C[4];

    for (int step = 0; step < TT; ++step) {
        const float4 xr = *(const float4*)&sx[step * 16 + quad * 4];
#pragma unroll
        for (int tt2 = 0; tt2 < 4; ++tt2) {
            C[tt2][0] = fmaf(xr.x, wih4[tt2], bs4[tt2]);
            C[tt2][1] = fmaf(xr.y, wih4[tt2], bs4[tt2]);
            C[tt2][2] = fmaf(xr.z, wih4[tt2], bs4[tt2]);
            C[tt2][3] = fmaf(xr.w, wih4[tt2], bs4[tt2]);
        }

#pragma unroll
        for (int kc = 0; kc < 2; ++kc) {
            short8 Ah = *(const short8*)&hh[kc * 512 + ra];
            short8 Al = *(const short8*)&hl[kc * 512 + ra];
#pragma unroll
            for (int tt2 = 0; tt2 < 4; ++tt2) {
                C[tt2] = __builtin_amdgcn_mfma_f32_16x16x32_bf16(Ah, Bh[tt2][kc], C[tt2], 0, 0, 0);
                C[tt2] = __builtin_amdgcn_mfma_f32_16x16x32_bf16(Ah, Bl[tt2][kc], C[tt2], 0, 0, 0);
                C[tt2] = __builtin_amdgcn_mfma_f32_16x16x32_bf16(Al, Bh[tt2][kc], C[tt2], 0, 0, 0);
            }
        }

        // tanh = 1 - 2*rcp(exp2(2.885*a)+1)  (no clamp needed; inf-safe)
        // + trunc-split, direct per-lane ds_write_b16 into swizzled A layout
#pragma unroll
        for (int tt2 = 0; tt2 < 4; ++tt2) {
            const int kc_d = tt2 >> 1;
            const int qa   = (nl >> 3) + 2 * (tt2 & 1);
            const int jj   = nl & 7;
#pragma unroll
            for (int r = 0; r < 4; ++r) {
                float eg = __builtin_amdgcn_exp2f(C[tt2][r] * 2.885390081777927f);
                float hv = fmaf(-2.0f, __builtin_amdgcn_rcpf(eg + 1.0f), 1.0f);
                C[tt2][r] = hv;
                unsigned um = fbits(hv);
                unsigned hb = um & 0xffff0000u;
                float lo = hv - bcast(hb);
                const int m   = quad * 4 + r;
                const int la  = m + 16 * qa;
                const int idx = kc_d * 512 + (la ^ ((la >> 4) & 1)) * 8 + jj;
                hh[idx] = (unsigned short)(um >> 16);
                hl[idx] = (unsigned short)(fbits(lo) >> 16);
            }
        }
    }

    // epilogue: z = h.v
#pragma unroll
    for (int r = 0; r < 4; ++r) {
        float p = 0.0f;
#pragma unroll
        for (int tt2 = 0; tt2 < 4; ++tt2) p = fmaf(C[tt2][r], vv[tt2], p);
        p += __shfl_xor(p, 1, 64);
        p += __shfl_xor(p, 2, 64);
        p += __shfl_xor(p, 4, 64);
        p += __shfl_xor(p, 8, 64);
        if (nl == 0) {
            const int n = n0 + quad * 4 + r;
            if (n < N) z[n] = p;
        }
    }
}

// reduce packed-u16 deg replicas; dinv = rsqrt(deg+1); w = dinv*z
__global__ __launch_bounds__(256) void k_w(const unsigned* __restrict__ degrep,
                                           const float* __restrict__ z,
                                           float* __restrict__ dinv,
                                           float* __restrict__ w, int N, int N2) {
    int n = blockIdx.x * blockDim.x + threadIdx.x;
    if (n >= N) return;
    const int wd = n >> 1, sh = (n & 1) << 4;
    unsigned d = 0;
#pragma unroll 8
    for (int s = 0; s < NSL; ++s) d += (degrep[(size_t)s * N2 + wd] >> sh) & 0xffffu;
    float di = __frsqrt_rn((float)d + 1.0f);
    dinv[n] = di;
    w[n] = di * z[n];
}

// S aggregation via fp32 LDS bins (range, slice), replica-overwrite flush.
__global__ __launch_bounds__(1024) void k_edge_bin(const int* __restrict__ ei,
                                                   const float* __restrict__ w,
                                                   float* __restrict__ Srep,
                                                   int N, int E, int R) {
    __shared__ float bin[RSZ];                    // 64 KB
    const int r = blockIdx.x % R;
    const int s = blockIdx.x / R;
    const int base = r * RSZ;
    for (int i = threadIdx.x; i < RSZ; i += 1024) bin[i] = 0.0f;
    __syncthreads();
    const long long eb = (long long)s * E / NSL;
    const long long ee = (long long)(s + 1) * E / NSL;
    const int2* ei2 = (const int2*)ei;
    for (long long e = eb + threadIdx.x; e < ee; e += 1024) {
        int2 p = ei2[e];
        unsigned u = (unsigned)(p.y - base);
        if (u < RSZ) atomicAdd(&bin[u], w[p.x]);
    }
    __syncthreads();
    const int lim = min(RSZ, N - base);
    float* dst = Srep + (size_t)s * N + base;
    for (int i = threadIdx.x; i < lim; i += 1024) dst[i] = bin[i];
}

// out = dinv*(sum S_rep) + dinv*w + c,  c = w_fc.b_gcn + b_fc
__global__ __launch_bounds__(256) void k_final(const float* __restrict__ dinv,
                                               const float* __restrict__ Srep,
                                               const float* __restrict__ w,
                                               const float* __restrict__ b_gcn,
                                               const float* __restrict__ W_fc,
                                               const float* __restrict__ b_fc,
                                               float* __restrict__ out, int N)
{
    float c = b_fc[0];
#pragma unroll 8
    for (int j = 0; j < HH; ++j) c = fmaf(W_fc[j], b_gcn[j], c);
    int n = blockIdx.x * blockDim.x + threadIdx.x;
    if (n >= N) return;
    float S = 0.0f;
#pragma unroll 8
    for (int s = 0; s < NSL; ++s) S += Srep[(size_t)s * N + n];
    float d = dinv[n];
    out[n] = fmaf(d, S, fmaf(d, w[n], c));
}

extern "C" void kernel_launch(void* const* d_in, const int* in_sizes, int n_in,
                              void* d_out, int out_size, void* d_ws, size_t ws_size,
                              hipStream_t stream)
{
    const float* x     = (const float*)d_in[0];
    const int*   ei    = (const int*)d_in[1];
    const float* W_ih  = (const float*)d_in[2];
    const float* b_ih  = (const float*)d_in[3];
    const float* W_hh  = (const float*)d_in[4];
    const float* b_hh  = (const float*)d_in[5];
    const float* W_gcn = (const float*)d_in[6];
    const float* b_gcn = (const float*)d_in[7];
    const float* W_fc  = (const float*)d_in[8];
    const float* b_fc  = (const float*)d_in[9];
    float* out = (float*)d_out;

    const int N  = in_sizes[0] / TT;
    const int E  = in_sizes[1] / 2;
    const int N2 = (N + 1) / 2;
    const int RD = (N + DRSZ - 1) / DRSZ;      // deg ranges (u16 bins)
    const int RS = (N + RSZ - 1) / RSZ;        // S ranges (fp32 bins)

    char* ws = (char*)d_ws;
    size_t off = 0;
    auto alloc = [&](size_t bytes) { void* p = ws + off; off += (bytes + 255) & ~(size_t)255; return p; };
    unsigned* degrep = (unsigned*)alloc((size_t)NSL * N2 * 4);   // packed u16 pairs
    float*    Srep   = (float*)   alloc((size_t)NSL * N * 4);
    float*    z      = (float*)   alloc((size_t)N * 4);
    float*    dinv   = (float*)   alloc((size_t)N * 4);
    float*    w      = (float*)   alloc((size_t)N * 4);
    // no memsets: every replica byte is overwritten by its (range, slice) owner

    const int rnnBlocks = (N + 63) / 64;
    k_deg_bin <<<RD * NSL, 1024, 0, stream>>>(ei, degrep, N, E, RD, N2);
    k_rnn     <<<rnnBlocks, 256, 0, stream>>>(x, W_ih, b_ih, W_hh, b_hh,
                                              W_gcn, W_fc, z, N);
    k_w       <<<(N + 255) / 256, 256, 0, stream>>>(degrep, z, dinv, w, N, N2);
    k_edge_bin<<<RS * NSL, 1024, 0, stream>>>(ei, w, Srep, N, E, RS);
    k_final   <<<(N + 255) / 256, 256, 0, stream>>>(dinv, Srep, w, b_gcn, W_fc, b_fc, out, N);
}

// Round 15
// 221.171 us; speedup vs baseline: 6.7525x; 1.1087x over previous
//
#include <hip/hip_runtime.h>

#define TT 20
#define HH 64
#define RSZ 16384      // fp32 S-bin range (64 KB LDS)
#define DRSZ 16384     // u16 deg-bin range (32 KB LDS, shared with RNN path)
#define NSL 64         // edge slices for S pass
#define NSLD 32        // edge slices for fused deg pass

typedef __attribute__((ext_vector_type(8))) short short8;   // 8 bf16 (MFMA A/B frag)
typedef __attribute__((ext_vector_type(4))) float f32x4;    // MFMA C/D frag

__device__ __forceinline__ unsigned fbits(float f) { union { float f; unsigned u; } v; v.f = f; return v.u; }
__device__ __forceinline__ float bcast(unsigned u) { union { float f; unsigned u; } v; v.u = u; return v.f; }

// Fused: blocks [0, RD*NSLD) = deg histogram via LDS u16 bins (VMEM/L3 pipes);
// blocks >= RD*NSLD = pure MFMA RNN (VALU/LDS/MFMA pipes). One 32 KB smem pool.
__global__ __launch_bounds__(256, 3) void k_fused(
    const float* __restrict__ x,
    const float* __restrict__ W_ih, const float* __restrict__ b_ih,
    const float* __restrict__ W_hh, const float* __restrict__ b_hh,
    const float* __restrict__ W_gcn, const float* __restrict__ W_fc,
    const int* __restrict__ ei, unsigned* __restrict__ degrep,
    float* __restrict__ z, int N, int E, int RD, int N2)
{
    __shared__ __align__(16) unsigned smem[8192];   // 32 KB

    const int t = threadIdx.x;
    const int RDN = RD * NSLD;

    if (blockIdx.x < RDN) {
        // ---- deg histogram: packed-u16 LDS bins, int4 = 2 edges per load ----
        unsigned* bin = smem;                       // 8192 words = 16384 u16 bins
        const int r = blockIdx.x % RD;
        const int s = blockIdx.x / RD;
        const int base = r * DRSZ;
        for (int i = t; i < DRSZ / 2; i += 256) bin[i] = 0;
        __syncthreads();
        const long long P = (long long)(E >> 1);
        const long long pb = s * P / NSLD;
        const long long pe = (s + 1) * P / NSLD;
        const int4* ei4 = (const int4*)ei;
        for (long long g = pb + t; g < pe; g += 256) {
            int4 q = ei4[g];
            unsigned u0 = (unsigned)(q.y - base);
            unsigned u1 = (unsigned)(q.w - base);
            if (u0 < DRSZ) atomicAdd(&bin[u0 >> 1], 1u << ((u0 & 1) << 4));
            if (u1 < DRSZ) atomicAdd(&bin[u1 >> 1], 1u << ((u1 & 1) << 4));
        }
        if ((E & 1) && s == NSLD - 1 && t == 0) {
            unsigned u = (unsigned)(ei[2 * (E - 1) + 1] - base);
            if (u < DRSZ) atomicAdd(&bin[u >> 1], 1u << ((u & 1) << 4));
        }
        __syncthreads();
        const int lim = min(DRSZ, N - base);
        const int words = (lim + 1) >> 1;
        unsigned* dst = degrep + (size_t)s * N2 + (base >> 1);
        for (int i = t; i < words; i += 256) dst[i] = bin[i];
        return;
    }

    // ---- MFMA RNN: 4 independent waves, 16 nodes each, wave-private LDS ----
    const int w    = t >> 6;
    const int l    = t & 63;
    const int nl   = l & 15;
    const int quad = l >> 4;
    const int n0   = (blockIdx.x - RDN) * 64 + w * 16;

    unsigned short* hh = (unsigned short*)&smem[w * 512];          // 1024 u16
    unsigned short* hl = (unsigned short*)&smem[2048 + w * 512];   // 1024 u16
    float*          sx = (float*)&smem[4096 + w * 320];            // 320 f32

    // stage x (16 nodes x 20 steps, transposed [step][node])
    for (int i = l; i < 16 * TT; i += 64) {
        int nn = i / TT, tt = i - nn * TT;
        int n = n0 + nn; if (n >= N) n = N - 1;
        sx[tt * 16 + nn] = x[(size_t)n * TT + tt];
    }
    // zero h
    {
        uint4 zz = {0, 0, 0, 0};
        uint4* ph = (uint4*)hh;
        uint4* pl = (uint4*)hl;
#pragma unroll
        for (int i = 0; i < 2; ++i) { ph[l + 64 * i] = zz; pl[l + 64 * i] = zz; }
    }

    // W_hh -> hi/lo bf16 B-fragments (registers, trunc-split)
    short8 Bh[4][2], Bl[4][2];
#pragma unroll
    for (int tt2 = 0; tt2 < 4; ++tt2)
#pragma unroll
        for (int kc = 0; kc < 2; ++kc) {
            const float* wr = W_hh + (size_t)(16 * tt2 + nl) * HH + kc * 32 + quad * 8;
            float4 w0 = *(const float4*)(wr);
            float4 w1 = *(const float4*)(wr + 4);
            float wvv[8] = {w0.x, w0.y, w0.z, w0.w, w1.x, w1.y, w1.z, w1.w};
            short8 sh, sl;
#pragma unroll
            for (int j = 0; j < 8; ++j) {
                unsigned u  = fbits(wvv[j]);
                unsigned hb = u & 0xffff0000u;
                float lo = wvv[j] - bcast(hb);
                sh[j] = (short)(hb >> 16);
                sl[j] = (short)(fbits(lo) >> 16);
            }
            Bh[tt2][kc] = sh; Bl[tt2][kc] = sl;
        }

    // v = W_gcn^T w_fc
    float vl = 0.0f;
#pragma unroll 8
    for (int j = 0; j < HH; ++j) vl = fmaf(W_fc[j], W_gcn[j * HH + l], vl);

    float wih4[4], bs4[4], vv[4];
#pragma unroll
    for (int tt2 = 0; tt2 < 4; ++tt2) {
        int n = nl + 16 * tt2;
        wih4[tt2] = W_ih[n];
        bs4[tt2]  = b_ih[n] + b_hh[n];
        vv[tt2]   = __shfl(vl, n, 64);
    }

    const int ra = (l ^ ((l >> 4) & 1)) * 8;   // A-read offset (shorts)

    f32x4 C[4];

    for (int step = 0; step < TT; ++step) {
        const float4 xr = *(const float4*)&sx[step * 16 + quad * 4];
#pragma unroll
        for (int tt2 = 0; tt2 < 4; ++tt2) {
            C[tt2][0] = fmaf(xr.x, wih4[tt2], bs4[tt2]);
            C[tt2][1] = fmaf(xr.y, wih4[tt2], bs4[tt2]);
            C[tt2][2] = fmaf(xr.z, wih4[tt2], bs4[tt2]);
            C[tt2][3] = fmaf(xr.w, wih4[tt2], bs4[tt2]);
        }

#pragma unroll
        for (int kc = 0; kc < 2; ++kc) {
            short8 Ah = *(const short8*)&hh[kc * 512 + ra];
            short8 Al = *(const short8*)&hl[kc * 512 + ra];
#pragma unroll
            for (int tt2 = 0; tt2 < 4; ++tt2) {
                C[tt2] = __builtin_amdgcn_mfma_f32_16x16x32_bf16(Ah, Bh[tt2][kc], C[tt2], 0, 0, 0);
                C[tt2] = __builtin_amdgcn_mfma_f32_16x16x32_bf16(Ah, Bl[tt2][kc], C[tt2], 0, 0, 0);
                C[tt2] = __builtin_amdgcn_mfma_f32_16x16x32_bf16(Al, Bh[tt2][kc], C[tt2], 0, 0, 0);
            }
        }

        // tanh = 1 - 2*rcp(exp2(2.885*a)+1); trunc-split; per-lane ds_write_b16
#pragma unroll
        for (int tt2 = 0; tt2 < 4; ++tt2) {
            const int kc_d = tt2 >> 1;
            const int qa   = (nl >> 3) + 2 * (tt2 & 1);
            const int jj   = nl & 7;
#pragma unroll
            for (int r = 0; r < 4; ++r) {
                float eg = __builtin_amdgcn_exp2f(C[tt2][r] * 2.885390081777927f);
                float hv = fmaf(-2.0f, __builtin_amdgcn_rcpf(eg + 1.0f), 1.0f);
                C[tt2][r] = hv;
                unsigned um = fbits(hv);
                unsigned hb = um & 0xffff0000u;
                float lo = hv - bcast(hb);
                const int m   = quad * 4 + r;
                const int la  = m + 16 * qa;
                const int idx = kc_d * 512 + (la ^ ((la >> 4) & 1)) * 8 + jj;
                hh[idx] = (unsigned short)(um >> 16);
                hl[idx] = (unsigned short)(fbits(lo) >> 16);
            }
        }
    }

    // epilogue: z = h.v
#pragma unroll
    for (int r = 0; r < 4; ++r) {
        float p = 0.0f;
#pragma unroll
        for (int tt2 = 0; tt2 < 4; ++tt2) p = fmaf(C[tt2][r], vv[tt2], p);
        p += __shfl_xor(p, 1, 64);
        p += __shfl_xor(p, 2, 64);
        p += __shfl_xor(p, 4, 64);
        p += __shfl_xor(p, 8, 64);
        if (nl == 0) {
            const int n = n0 + quad * 4 + r;
            if (n < N) z[n] = p;
        }
    }
}

// reduce packed-u16 deg replicas; dinv = rsqrt(deg+1); w = dinv*z
__global__ __launch_bounds__(256) void k_w(const unsigned* __restrict__ degrep,
                                           const float* __restrict__ z,
                                           float* __restrict__ dinv,
                                           float* __restrict__ w, int N, int N2) {
    int n = blockIdx.x * blockDim.x + threadIdx.x;
    if (n >= N) return;
    const int wd = n >> 1, sh = (n & 1) << 4;
    unsigned d = 0;
#pragma unroll 8
    for (int s = 0; s < NSLD; ++s) d += (degrep[(size_t)s * N2 + wd] >> sh) & 0xffffu;
    float di = __frsqrt_rn((float)d + 1.0f);
    dinv[n] = di;
    w[n] = di * z[n];
}

// S aggregation via fp32 LDS bins; int4 = 2 edges per load.
__global__ __launch_bounds__(1024) void k_edge_bin(const int* __restrict__ ei,
                                                   const float* __restrict__ w,
                                                   float* __restrict__ Srep,
                                                   int N, int E, int R) {
    __shared__ float bin[RSZ];                    // 64 KB
    const int r = blockIdx.x % R;
    const int s = blockIdx.x / R;
    const int base = r * RSZ;
    for (int i = threadIdx.x; i < RSZ; i += 1024) bin[i] = 0.0f;
    __syncthreads();
    const long long P = (long long)(E >> 1);
    const long long pb = s * P / NSL;
    const long long pe = (s + 1) * P / NSL;
    const int4* ei4 = (const int4*)ei;
    for (long long g = pb + threadIdx.x; g < pe; g += 1024) {
        int4 q = ei4[g];
        unsigned u0 = (unsigned)(q.y - base);
        unsigned u1 = (unsigned)(q.w - base);
        if (u0 < RSZ) atomicAdd(&bin[u0], w[q.x]);
        if (u1 < RSZ) atomicAdd(&bin[u1], w[q.z]);
    }
    if ((E & 1) && s == NSL - 1 && threadIdx.x == 0) {
        unsigned u = (unsigned)(ei[2 * (E - 1) + 1] - base);
        if (u < RSZ) atomicAdd(&bin[u], w[ei[2 * (E - 1)]]);
    }
    __syncthreads();
    const int lim = min(RSZ, N - base);
    float* dst = Srep + (size_t)s * N + base;
    for (int i = threadIdx.x; i < lim; i += 1024) dst[i] = bin[i];
}

// out = dinv*(sum S_rep) + dinv*w + c,  c = w_fc.b_gcn + b_fc
__global__ __launch_bounds__(256) void k_final(const float* __restrict__ dinv,
                                               const float* __restrict__ Srep,
                                               const float* __restrict__ w,
                                               const float* __restrict__ b_gcn,
                                               const float* __restrict__ W_fc,
                                               const float* __restrict__ b_fc,
                                               float* __restrict__ out, int N)
{
    float c = b_fc[0];
#pragma unroll 8
    for (int j = 0; j < HH; ++j) c = fmaf(W_fc[j], b_gcn[j], c);
    int n = blockIdx.x * blockDim.x + threadIdx.x;
    if (n >= N) return;
    float S = 0.0f;
#pragma unroll 8
    for (int s = 0; s < NSL; ++s) S += Srep[(size_t)s * N + n];
    float d = dinv[n];
    out[n] = fmaf(d, S, fmaf(d, w[n], c));
}

extern "C" void kernel_launch(void* const* d_in, const int* in_sizes, int n_in,
                              void* d_out, int out_size, void* d_ws, size_t ws_size,
                              hipStream_t stream)
{
    const float* x     = (const float*)d_in[0];
    const int*   ei    = (const int*)d_in[1];
    const float* W_ih  = (const float*)d_in[2];
    const float* b_ih  = (const float*)d_in[3];
    const float* W_hh  = (const float*)d_in[4];
    const float* b_hh  = (const float*)d_in[5];
    const float* W_gcn = (const float*)d_in[6];
    const float* b_gcn = (const float*)d_in[7];
    const float* W_fc  = (const float*)d_in[8];
    const float* b_fc  = (const float*)d_in[9];
    float* out = (float*)d_out;

    const int N  = in_sizes[0] / TT;
    const int E  = in_sizes[1] / 2;
    const int N2 = (N + 1) / 2;
    const int RD = (N + DRSZ - 1) / DRSZ;      // deg ranges (u16 bins, 32 KB)
    const int RS = (N + RSZ - 1) / RSZ;        // S ranges (fp32 bins, 64 KB)

    char* ws = (char*)d_ws;
    size_t off = 0;
    auto alloc = [&](size_t bytes) { void* p = ws + off; off += (bytes + 255) & ~(size_t)255; return p; };
    unsigned* degrep = (unsigned*)alloc((size_t)NSLD * N2 * 4);  // packed u16 pairs
    float*    Srep   = (float*)   alloc((size_t)NSL * N * 4);
    float*    z      = (float*)   alloc((size_t)N * 4);
    float*    dinv   = (float*)   alloc((size_t)N * 4);
    float*    w      = (float*)   alloc((size_t)N * 4);
    // no memsets: every replica byte is overwritten by its (range, slice) owner

    const int rnnBlocks = (N + 63) / 64;
    k_fused   <<<RD * NSLD + rnnBlocks, 256, 0, stream>>>(x, W_ih, b_ih, W_hh, b_hh,
                                                          W_gcn, W_fc, ei, degrep,
                                                          z, N, E, RD, N2);
    k_w       <<<(N + 255) / 256, 256, 0, stream>>>(degrep, z, dinv, w, N, N2);
    k_edge_bin<<<RS * NSL, 1024, 0, stream>>>(ei, w, Srep, N, E, RS);
    k_final   <<<(N + 255) / 256, 256, 0, stream>>>(dinv, Srep, w, b_gcn, W_fc, b_fc, out, N);
}